// Round 6
// baseline (248.465 us; speedup 1.0000x reference)
//
#include <hip/hip_runtime.h>
#include <math.h>
#include <stdint.h>

#define NB 15
#define TROWS 256                 // rows per tile (1 per thread)
#define TBYTES (TROWS * 40)       // 10240 B per tile
#define NCOPY 8                   // spread accumulator copies (contention /8)
#define ACCSTRIDE 64              // floats per copy

// d_ws: NCOPY copies of [0..14]=counts, [15..29]=sum_u, [30..44]=sum_err

__device__ __forceinline__ void gload_lds16(const void* g, float* ldsBase, uint32_t ldsByteOff)
{
    // async global->LDS, 16 B/lane; LDS dest = wave-uniform base + lane*16 (HW)
    __builtin_amdgcn_global_load_lds(
        (const __attribute__((address_space(1))) uint32_t*)g,
        (__attribute__((address_space(3))) uint32_t*)((char*)ldsBase + ldsByteOff),
        16, 0, 0);
}

__global__ __launch_bounds__(256) void bin_kernel(
    const float* __restrict__ logits,
    const int* __restrict__ labels,
    float* __restrict__ acc,
    int N, int numTiles)
{
    __shared__ float lds[2][TROWS * 10];   // 2 x 10240 B, unpadded (DMA layout)
    __shared__ float s_acc[3 * NB];

    const int t = threadIdx.x;
    if (t < 3 * NB) s_acc[t] = 0.0f;
    const int wid  = t >> 6;
    const int lane = t & 63;

    // nibble-packed counts/errors: cnt01 = bins 0..7, cnt89 = bins 8..14 (max 9/bin/thread)
    unsigned cnt01 = 0, cnt89 = 0, err01 = 0, err89 = 0;
    float su[NB];
#pragma unroll
    for (int b = 0; b < NB; ++b) su[b] = 0.0f;

    const char* srcB = (const char*)logits;
    const long long totB = (long long)N * 40;
    const int k0 = wid, k1 = wid + 4, k2 = wid + 8;   // chunk ids for this wave

    // ---- prologue: issue tile0 DMA into buf0, prefetch its label ----
    int tile = blockIdx.x;
    {
        const long long tb = (long long)tile * TBYTES;
        long long gb0 = tb + (k0 << 10) + lane * 16;
        long long gb1 = tb + (k1 << 10) + lane * 16;
        if (gb0 < totB) gload_lds16(srcB + gb0, (float*)lds, __builtin_amdgcn_readfirstlane((uint32_t)(k0 << 10)));
        if (gb1 < totB) gload_lds16(srcB + gb1, (float*)lds, __builtin_amdgcn_readfirstlane((uint32_t)(k1 << 10)));
        if (k2 < 10) {
            long long gb2 = tb + (k2 << 10) + lane * 16;
            if (gb2 < totB) gload_lds16(srcB + gb2, (float*)lds, __builtin_amdgcn_readfirstlane((uint32_t)(k2 << 10)));
        }
    }
    int r0 = tile * TROWS + t;
    int labCur = (r0 < N) ? labels[r0] : 0;

    int cur = 0;
    for (; tile < numTiles; tile += gridDim.x) {
        const int nxt = tile + gridDim.x;

        __syncthreads();     // drains this wave's DMA -> buf[cur] valid; buf[cur^1] free

        // ---- issue next tile's DMA into the other buffer (latency hidden by compute) ----
        int labNext = 0;
        if (nxt < numTiles) {
            const long long tb = (long long)nxt * TBYTES;
            const uint32_t bufOff = (uint32_t)((cur ^ 1) * TBYTES);
            long long gb0 = tb + (k0 << 10) + lane * 16;
            long long gb1 = tb + (k1 << 10) + lane * 16;
            if (gb0 < totB) gload_lds16(srcB + gb0, (float*)lds, __builtin_amdgcn_readfirstlane(bufOff + (k0 << 10)));
            if (gb1 < totB) gload_lds16(srcB + gb1, (float*)lds, __builtin_amdgcn_readfirstlane(bufOff + (k1 << 10)));
            if (k2 < 10) {
                long long gb2 = tb + (k2 << 10) + lane * 16;
                if (gb2 < totB) gload_lds16(srcB + gb2, (float*)lds, __builtin_amdgcn_readfirstlane(bufOff + (k2 << 10)));
            }
            int rn = nxt * TROWS + t;
            labNext = (rn < N) ? labels[rn] : 0;
        }

        // ---- compute own row from buf[cur] ----
        const int r = tile * TROWS + t;
        const bool rowOK = (r < N);
        const float* rp = lds[cur] + t * 10;
        float lv[10];
        {
            const float2* p2 = (const float2*)rp;
#pragma unroll
            for (int j = 0; j < 5; ++j) { float2 w = p2[j]; lv[2*j] = w.x; lv[2*j+1] = w.y; }
        }
        float m = lv[0];
#pragma unroll
        for (int j = 1; j < 10; ++j) m = fmaxf(m, lv[j]);

        const float c = 1.44269504088896340736f;
        float mc = m * c;
        float Z = 0.0f, S = 0.0f;
#pragma unroll
        for (int j = 0; j < 10; ++j) {
            float e = exp2f(fmaf(lv[j], c, -mc));
            Z += e;
            S = fmaf(e, e, S);
        }
        float ratio = S * __builtin_amdgcn_rcpf(Z * Z);   // sum(p^2)
        float u = -log2f(ratio + 1e-12f);

        bool valid = rowOK && (u >= 0.0f) && (u < 1.0f);
        int bin = -1;
        if (valid) {
            bin = (int)(u * 15.0f);
            if (bin > 14) bin = 14;
        }
        float uu = valid ? u : 0.0f;

        float lvl = rp[labCur];                   // label's logit, dynamic LDS read
        bool e10 = (lvl != m);                    // wrong iff label's logit isn't the max

        unsigned nib = valid ? (1u << ((bin & 7) << 2)) : 0u;
        bool lo = ((unsigned)bin < 8u);           // bin=-1 -> false; nib=0 anyway
        cnt01 += lo ? nib : 0u;
        cnt89 += lo ? 0u : nib;
        unsigned en = e10 ? nib : 0u;
        err01 += lo ? en : 0u;
        err89 += lo ? 0u : en;
#pragma unroll
        for (int b = 0; b < NB; ++b)
            su[b] += (bin == b) ? uu : 0.0f;

        cur ^= 1;
        labCur = labNext;
    }

    // ---- epilogue: unpack nibbles, wave butterfly, shared atomics, spread global atomics
#pragma unroll
    for (int b = 0; b < NB; ++b) {
        unsigned c4 = (b < 8) ? (cnt01 >> (b * 4)) : (cnt89 >> ((b - 8) * 4));
        unsigned e4 = (b < 8) ? (err01 >> (b * 4)) : (err89 >> ((b - 8) * 4));
        int   p = (int)((c4 & 15u) | ((e4 & 15u) << 16));
        float s = su[b];
#pragma unroll
        for (int off = 1; off < 64; off <<= 1) {
            p += __shfl_xor(p, off, 64);
            s += __shfl_xor(s, off, 64);
        }
        if (lane == 0) {
            atomicAdd(&s_acc[b],          (float)(p & 0xFFFF));
            atomicAdd(&s_acc[NB + b],     s);
            atomicAdd(&s_acc[2 * NB + b], (float)((unsigned)p >> 16));
        }
    }
    __syncthreads();
    if (t < 3 * NB) {
        float v = s_acc[t];
        if (v != 0.0f)
            atomicAdd(&acc[(blockIdx.x & (NCOPY - 1)) * ACCSTRIDE + t], v);
    }
}

__global__ void finalize_kernel(const float* __restrict__ acc,
                                float* __restrict__ out, float n)
{
    int b = threadIdx.x;
    float gap = 0.0f;
    if (b < NB) {
        float cnt = 0.0f, sumu = 0.0f, serr = 0.0f;
#pragma unroll
        for (int c = 0; c < NCOPY; ++c) {
            cnt  += acc[c * ACCSTRIDE + b];
            sumu += acc[c * ACCSTRIDE + NB + b];
            serr += acc[c * ACCSTRIDE + 2 * NB + b];
        }
        if (cnt > 0.0f) {
            float u_b   = sumu / cnt;
            float err_b = serr / cnt;
            float inner = 2.0f * exp2f(-u_b) - 1.0f;
            if (inner < 0.0f) inner = 0.0f;
            float r_ref = 0.5f * (1.0f - sqrtf(inner));
            gap = fabsf(err_b - r_ref) * (cnt / n);
        }
    }
#pragma unroll
    for (int off = 32; off >= 1; off >>= 1)
        gap += __shfl_xor(gap, off, 64);
    if (b == 0) out[0] = gap;
}

extern "C" void kernel_launch(void* const* d_in, const int* in_sizes, int n_in,
                              void* d_out, int out_size, void* d_ws, size_t ws_size,
                              hipStream_t stream)
{
    const float* logits = (const float*)d_in[0];
    const int*   labels = (const int*)d_in[1];
    const int N = in_sizes[1];                  // labels count = number of rows

    float* acc = (float*)d_ws;                  // NCOPY * ACCSTRIDE floats
    hipMemsetAsync(acc, 0, NCOPY * ACCSTRIDE * sizeof(float), stream);

    const int numTiles = (N + TROWS - 1) / TROWS;
    // 1792 = 7 blocks/CU (LDS-limited: 2x10240B + s_acc). Max 9 tiles/thread -> nibble-safe (<15).
    int blocks = numTiles < 1792 ? numTiles : 1792;
    bin_kernel<<<blocks, 256, 0, stream>>>(logits, labels, acc, N, numTiles);
    finalize_kernel<<<1, 64, 0, stream>>>(acc, (float*)d_out, (float)N);
}

// Round 7
// 246.521 us; speedup vs baseline: 1.0079x; 1.0079x over previous
//
#include <hip/hip_runtime.h>
#include <math.h>
#include <stdint.h>

#define NB 15
#define NCOPY 8
#define ACCSTRIDE 64

// microtile = 128 rows = 5120 B = exactly 5 DMA chunks of (64 lanes x 16 B).
// Per-wave private segments (1280 floats) in two static LDS arrays (A/B pipeline).
// No barriers in the loop; all VMEM unconditional -> compiler emits exact vmcnt(7).

__device__ __forceinline__ void dma16(const char* g, float* ldsArr, uint32_t byteOff)
{
    __builtin_amdgcn_global_load_lds(
        (const __attribute__((address_space(1))) uint32_t*)g,
        (__attribute__((address_space(3))) uint32_t*)((char*)ldsArr + byteOff),
        16, 0, 0);
}

__device__ __forceinline__ void stage_mt(const char* srcB, long long clampHi,
                                         float* ldsArr, uint32_t segOff,
                                         long long mClamped, int lane)
{
    long long g0 = mClamped * 5120 + (long long)lane * 16;
#pragma unroll
    for (int c = 0; c < 5; ++c) {
        long long g = g0 + c * 1024;
        g = (g > clampHi) ? clampHi : g;     // unconditional vmem (exact waitcnt counts)
        dma16(srcB + g, ldsArr, segOff + (uint32_t)(c * 1024));
    }
}

__device__ __forceinline__ void load_labs(const int* __restrict__ labels, long long mClamped,
                                          int lane, int N, int& la0, int& la1)
{
    long long r0 = mClamped * 128 + lane;
    long long r1 = r0 + 64;
    r0 = (r0 < N) ? r0 : (N - 1);            // clamp, keep loads unconditional
    r1 = (r1 < N) ? r1 : (N - 1);
    la0 = labels[r0];
    la1 = labels[r1];
}

__device__ __forceinline__ void row_math(const float lv[10], float lvl, bool rowOK,
                                         int& bin, float& uu, bool& e10)
{
    float m = lv[0];
#pragma unroll
    for (int j = 1; j < 10; ++j) m = fmaxf(m, lv[j]);
    const float c = 1.44269504088896340736f;
    float mc = m * c;
    float Z = 0.0f, S = 0.0f;
#pragma unroll
    for (int j = 0; j < 10; ++j) {
        float e = exp2f(fmaf(lv[j], c, -mc));
        Z += e;
        S = fmaf(e, e, S);
    }
    float ratio = S * __builtin_amdgcn_rcpf(Z * Z);   // sum(p^2)
    float u = -log2f(ratio + 1e-12f);
    bool valid = rowOK && (u >= 0.0f) && (u < 1.0f);
    bin = -1;
    if (valid) {
        bin = (int)(u * 15.0f);
        if (bin > 14) bin = 14;
    }
    uu = valid ? u : 0.0f;
    e10 = (lvl != m);                         // wrong iff label's logit isn't the max
}

__device__ __forceinline__ void accum(int bin, float uu, bool e10,
                                      unsigned& c01, unsigned& c89,
                                      unsigned& e01, unsigned& e89, float su[NB])
{
    unsigned nib = (bin >= 0) ? (1u << ((bin & 7) << 2)) : 0u;
    bool lo = ((unsigned)bin < 8u);           // bin=-1 -> false, nib=0 anyway
    c01 += lo ? nib : 0u;
    c89 += lo ? 0u : nib;
    unsigned en = e10 ? nib : 0u;
    e01 += lo ? en : 0u;
    e89 += lo ? 0u : en;
#pragma unroll
    for (int b = 0; b < NB; ++b)
        su[b] += (bin == b) ? uu : 0.0f;
}

__device__ __forceinline__ void consume_mt(const float* seg, int lane, long long kMT, int N,
                                           int la0, int la1,
                                           unsigned& c01a, unsigned& c89a, unsigned& e01a, unsigned& e89a,
                                           unsigned& c01b, unsigned& c89b, unsigned& e01b, unsigned& e89b,
                                           float su[NB])
{
    const float* r0p = seg + lane * 10;
    const float* r1p = seg + (lane + 64) * 10;
    float lv0[10], lv1[10];
    {
        const float2* p0 = (const float2*)r0p;
        const float2* p1 = (const float2*)r1p;
#pragma unroll
        for (int j = 0; j < 5; ++j) {
            float2 w0 = p0[j]; lv0[2*j] = w0.x; lv0[2*j+1] = w0.y;
            float2 w1 = p1[j]; lv1[2*j] = w1.x; lv1[2*j+1] = w1.y;
        }
    }
    float lvl0 = r0p[la0];
    float lvl1 = r1p[la1];

    long long r0 = kMT * 128 + lane;
    bool ok0 = r0 < N;
    bool ok1 = (r0 + 64) < N;

    int bin0, bin1; float uu0, uu1; bool e0, e1;
    row_math(lv0, lvl0, ok0, bin0, uu0, e0);
    row_math(lv1, lvl1, ok1, bin1, uu1, e1);
    accum(bin0, uu0, e0, c01a, c89a, e01a, e89a, su);
    accum(bin1, uu1, e1, c01b, c89b, e01b, e89b, su);
}

__global__ __launch_bounds__(256) void bin_kernel(
    const float* __restrict__ logits,
    const int* __restrict__ labels,
    float* __restrict__ acc,
    int N, long long M, long long strideW)
{
    __shared__ float bufA[4 * 1280];   // 20480 B
    __shared__ float bufB[4 * 1280];   // 20480 B
    __shared__ float s_acc[3 * NB];

    const int t = threadIdx.x;
    if (t < 3 * NB) s_acc[t] = 0.0f;
    __syncthreads();

    const int wid = t >> 6, lane = t & 63;
    const long long gw = (long long)blockIdx.x * 4 + wid;
    const char* srcB = (const char*)logits;
    const long long totB = (long long)N * 40;
    const long long clampHi = totB - 16;
    const uint32_t segOff = __builtin_amdgcn_readfirstlane((uint32_t)(wid * 5120));
    const float* segA = bufA + wid * 1280;
    const float* segB = bufB + wid * 1280;

    // per-thread accumulators: nibble counts per row-slot (<=15 microtiles/wave by grid sizing)
    unsigned c01a = 0, c89a = 0, e01a = 0, e89a = 0;
    unsigned c01b = 0, c89b = 0, e01b = 0, e89b = 0;
    float su[NB];
#pragma unroll
    for (int b = 0; b < NB; ++b) su[b] = 0.0f;

    // ---- prologue: stage microtiles gw (->A) and gw+strideW (->B) ----
    long long mA = (gw < M) ? gw : (M - 1);
    long long mBt = gw + strideW;
    long long mB = (mBt < M) ? mBt : (M - 1);
    int laA0, laA1, laB0, laB1;
    stage_mt(srcB, clampHi, bufA, segOff, mA, lane);
    load_labs(labels, mA, lane, N, laA0, laA1);
    stage_mt(srcB, clampHi, bufB, segOff, mB, lane);
    load_labs(labels, mB, lane, N, laB0, laB1);

    long long k = gw;
    while (k < M) {
        // ---- body A: consume microtile k from segA, then refill A with k+2s ----
        consume_mt(segA, lane, k, N, laA0, laA1,
                   c01a, c89a, e01a, e89a, c01b, c89b, e01b, e89b, su);
        long long mA2 = k + 2 * strideW;
        mA2 = (mA2 < M) ? mA2 : (M - 1);
        stage_mt(srcB, clampHi, bufA, segOff, mA2, lane);
        load_labs(labels, mA2, lane, N, laA0, laA1);

        // ---- body B ----
        long long kB = k + strideW;
        if (kB < M) {
            consume_mt(segB, lane, kB, N, laB0, laB1,
                       c01a, c89a, e01a, e89a, c01b, c89b, e01b, e89b, su);
            long long mB2 = k + 3 * strideW;
            mB2 = (mB2 < M) ? mB2 : (M - 1);
            stage_mt(srcB, clampHi, bufB, segOff, mB2, lane);
            load_labs(labels, mB2, lane, N, laB0, laB1);
        }
        k += 2 * strideW;
    }

    // ---- epilogue: unpack nibbles, wave butterfly, shared atomics, spread global ----
#pragma unroll
    for (int b = 0; b < NB; ++b) {
        unsigned ca = (b < 8) ? (c01a >> (b * 4)) : (c89a >> ((b - 8) * 4));
        unsigned cb = (b < 8) ? (c01b >> (b * 4)) : (c89b >> ((b - 8) * 4));
        unsigned ea = (b < 8) ? (e01a >> (b * 4)) : (e89a >> ((b - 8) * 4));
        unsigned eb = (b < 8) ? (e01b >> (b * 4)) : (e89b >> ((b - 8) * 4));
        int   p = (int)(((ca & 15u) + (cb & 15u)) | (((ea & 15u) + (eb & 15u)) << 16));
        float s = su[b];
#pragma unroll
        for (int off = 1; off < 64; off <<= 1) {
            p += __shfl_xor(p, off, 64);
            s += __shfl_xor(s, off, 64);
        }
        if (lane == 0) {
            atomicAdd(&s_acc[b],          (float)(p & 0xFFFF));
            atomicAdd(&s_acc[NB + b],     s);
            atomicAdd(&s_acc[2 * NB + b], (float)((unsigned)p >> 16));
        }
    }
    __syncthreads();
    if (t < 3 * NB) {
        float v = s_acc[t];
        if (v != 0.0f)
            atomicAdd(&acc[(blockIdx.x & (NCOPY - 1)) * ACCSTRIDE + t], v);
    }
}

__global__ void finalize_kernel(const float* __restrict__ acc,
                                float* __restrict__ out, float n)
{
    int b = threadIdx.x;
    float gap = 0.0f;
    if (b < NB) {
        float cnt = 0.0f, sumu = 0.0f, serr = 0.0f;
#pragma unroll
        for (int c = 0; c < NCOPY; ++c) {
            cnt  += acc[c * ACCSTRIDE + b];
            sumu += acc[c * ACCSTRIDE + NB + b];
            serr += acc[c * ACCSTRIDE + 2 * NB + b];
        }
        if (cnt > 0.0f) {
            float u_b   = sumu / cnt;
            float err_b = serr / cnt;
            float inner = 2.0f * exp2f(-u_b) - 1.0f;
            if (inner < 0.0f) inner = 0.0f;
            float r_ref = 0.5f * (1.0f - sqrtf(inner));
            gap = fabsf(err_b - r_ref) * (cnt / n);
        }
    }
#pragma unroll
    for (int off = 32; off >= 1; off >>= 1)
        gap += __shfl_xor(gap, off, 64);
    if (b == 0) out[0] = gap;
}

extern "C" void kernel_launch(void* const* d_in, const int* in_sizes, int n_in,
                              void* d_out, int out_size, void* d_ws, size_t ws_size,
                              hipStream_t stream)
{
    const float* logits = (const float*)d_in[0];
    const int*   labels = (const int*)d_in[1];
    const int N = in_sizes[1];                      // rows

    float* acc = (float*)d_ws;
    hipMemsetAsync(acc, 0, NCOPY * ACCSTRIDE * sizeof(float), stream);

    const long long M = ((long long)N + 127) / 128; // microtiles
    int blocks = 768;                               // 3 blocks/CU (41 KB LDS each)
    long long totW = (long long)blocks * 4;
    long long mpw = (M + totW - 1) / totW;          // microtiles per wave
    if (mpw > 15) {                                 // nibble-capacity guard
        totW = (M + 14) / 15;
        blocks = (int)((totW + 3) / 4);
        totW = (long long)blocks * 4;
    }
    bin_kernel<<<blocks, 256, 0, stream>>>(logits, labels, acc, N, M, totW);
    finalize_kernel<<<1, 64, 0, stream>>>(acc, (float*)d_out, (float)N);
}